// Round 13
// baseline (402.256 us; speedup 1.0000x reference)
//
#include <hip/hip_runtime.h>
#include <stdint.h>

#define PRE_K   6000
#define POST_K  1000
#define CAP     8192      // candidate buffer per batch
#define BINS    1024
#define ROWS    6016      // 94*64, padded row count for NMS
#define CH      94        // ROWS/64 chunks
#define SCH     ((CH + 3) / 4)   // 256-row super-chunks
#define RC_CH   32        // off-diag mask tiles computed only for rc < RC_CH (+band)
#define JSPLIT  4         // k_rank comparison-range split
#define NEGF    -1000000000.0f
#define IOU_EPS 16.0f     // f32 decision margin; f32 abs error bound ~2

// ---- helpers ----------------------------------------------------------------

__device__ __forceinline__ uint32_t orderf(float f) {
  uint32_t u = __float_as_uint(f);
  return (u & 0x80000000u) ? ~u : (u | 0x80000000u);
}

__device__ __forceinline__ int score_bin(float sc) {
  int bin = (int)floorf((sc + 12.0f) * ((float)BINS / 24.0f));
  return bin < 0 ? 0 : (bin > BINS - 1 ? BINS - 1 : bin);
}

__device__ __forceinline__ int bin_slot(int bin) {
  return ((bin & 15) << 6) | (bin >> 4);
}

__device__ __forceinline__ uint64_t shfl64(uint64_t v, int src) {
  return (uint64_t)__shfl((long long)v, src, 64);
}

// full double-precision decode, matching the float64 numpy reference
__device__ __forceinline__ void decode_box(
    const float* __restrict__ anchors, const float* __restrict__ deltas,
    const int* __restrict__ isz, int n, int b,
    double& x1, double& y1, double& x2, double& y2, bool& valid) {
  double ax1 = (double)anchors[4 * n + 0], ay1 = (double)anchors[4 * n + 1];
  double ax2 = (double)anchors[4 * n + 2], ay2 = (double)anchors[4 * n + 3];
  double aw = ax2 - ax1, ah = ay2 - ay1;
  double acx = ax1 + 0.5 * aw, acy = ay1 + 0.5 * ah;
  double tx = (double)deltas[4 * n + 0], ty = (double)deltas[4 * n + 1];
  double tw = (double)deltas[4 * n + 2], th = (double)deltas[4 * n + 3];
  tw = tw < -10.0 ? -10.0 : (tw > 10.0 ? 10.0 : tw);
  th = th < -10.0 ? -10.0 : (th > 10.0 ? 10.0 : th);
  double px = acx + tx * aw, py = acy + ty * ah;
  double pw = aw * exp(tw), ph = ah * exp(th);
  double H = (double)isz[2 * b + 0], W = (double)isz[2 * b + 1];
  double wm = W - 1.0, hm = H - 1.0;
  x1 = px - 0.5 * pw; y1 = py - 0.5 * ph;
  x2 = px + 0.5 * pw; y2 = py + 0.5 * ph;
  x1 = fmin(fmax(x1, 0.0), wm); x2 = fmin(fmax(x2, 0.0), wm);
  y1 = fmin(fmax(y1, 0.0), hm); y2 = fmin(fmax(y2, 0.0), hm);
  valid = (x2 - x1 >= 16.0) && (y2 - y1 >= 16.0);
}

// exact f64 suppression test (bit-identical to the verified R2 path)
__device__ __forceinline__ bool iou_exact(const double* __restrict__ tbox,
                                          const double* __restrict__ tarea,
                                          size_t ri, size_t ci) {
  const double* pr = &tbox[ri * 4];
  const double* pc = &tbox[ci * 4];
  double w = fmin(pr[2], pc[2]) - fmax(pr[0], pc[0]); w = w > 0.0 ? w : 0.0;
  double h = fmin(pr[3], pc[3]) - fmax(pr[1], pc[1]); h = h > 0.0 ? h : 0.0;
  double it = w * h;
  return it > 0.7 * (tarea[ri] + tarea[ci] - it + 1e-9);
}

// ---- kernels ----------------------------------------------------------------

__global__ void k_init(uint32_t* hist, uint32_t* cnt, uint32_t* prank, int B) {
  int i = blockIdx.x * blockDim.x + threadIdx.x;
  if (i < B * BINS) hist[i] = 0u;
  if (i < B) cnt[i] = 0u;
  if (i < B * CAP) prank[i] = 0u;
}

// Decode + validity + LDS-privatized histogram.
__global__ void __launch_bounds__(256) k_score(const float* __restrict__ anchors,
                                               const int* __restrict__ bix,
                                               const int* __restrict__ isz,
                                               const float* __restrict__ logits,
                                               const float* __restrict__ deltas,
                                               float* __restrict__ scores,
                                               uint32_t* __restrict__ hist, int N) {
  const int SPAN = 4096;
  int start = blockIdx.x * SPAN;
  int end = start + SPAN < N ? start + SPAN : N;
  __shared__ uint32_t lh[2][BINS];
  for (int i = threadIdx.x; i < 2 * BINS; i += 256) ((uint32_t*)lh)[i] = 0u;
  __shared__ int s_b0, s_b1;
  if (threadIdx.x == 0) { s_b0 = bix[start]; s_b1 = bix[end - 1]; }
  __syncthreads();
  int b0 = s_b0, b1 = s_b1;

  for (int n = start + (int)threadIdx.x; n < end; n += 256) {
    int b = bix[n];
    double x1, y1, x2, y2; bool valid;
    decode_box(anchors, deltas, isz, n, b, x1, y1, x2, y2, valid);
    float sc = valid ? logits[n] : NEGF;
    scores[n] = sc;
    if (valid) {
      int bin = score_bin(sc);
      if (b == b0)      atomicAdd(&lh[0][bin], 1u);
      else if (b == b1) atomicAdd(&lh[1][bin], 1u);
      else              atomicAdd(&hist[b * BINS + bin_slot(bin)], 1u);
    }
  }
  __syncthreads();
  for (int bin = threadIdx.x; bin < BINS; bin += 256) {
    uint32_t c0 = lh[0][bin];
    if (c0) atomicAdd(&hist[b0 * BINS + bin_slot(bin)], c0);
    if (b1 != b0) {
      uint32_t c1 = lh[1][bin];
      if (c1) atomicAdd(&hist[b1 * BINS + bin_slot(bin)], c1);
    }
  }
}

__global__ void k_scan(const uint32_t* __restrict__ hist, uint32_t* __restrict__ bstar) {
  __shared__ uint32_t s[BINS];
  __shared__ int bs;
  int b = blockIdx.x, t = threadIdx.x;
  s[t] = hist[b * BINS + bin_slot(t)];
  if (t == 0) bs = 0;
  __syncthreads();
  for (int off = 1; off < BINS; off <<= 1) {
    uint32_t v = (t + off < BINS) ? s[t + off] : 0u;
    __syncthreads();
    s[t] += v;
    __syncthreads();
  }
  if (s[t] >= PRE_K) atomicMax(&bs, t);
  __syncthreads();
  if (t == 0) bstar[b] = (uint32_t)bs;
}

// Block-aggregated compaction.
__global__ void __launch_bounds__(1024) k_compact(const float* __restrict__ scores,
                                                  const int* __restrict__ bix,
                                                  const uint32_t* __restrict__ bstar,
                                                  uint32_t* __restrict__ cnt,
                                                  uint64_t* __restrict__ cand, int N) {
  const int SPAN = 8192;
  int start = blockIdx.x * SPAN;
  int end = start + SPAN < N ? start + SPAN : N;
  __shared__ uint32_t lcnt[8], lbase[8];
  if (threadIdx.x < 8) lcnt[threadIdx.x] = 0u;
  __syncthreads();

  bool     predv[8];
  uint64_t keyv[8];
  uint32_t lposv[8];
  int      bv[8];
  int nt = 0;
  for (int base = start; base < end; base += 1024, nt++) {
    int n = base + (int)threadIdx.x;
    bool pred = false; int b = 0; uint64_t key = 0ull; uint32_t lp = 0u;
    if (n < end) {
      float sc = scores[n];
      if (sc > 0.5f * NEGF) {
        b = bix[n];
        if ((uint32_t)score_bin(sc) >= bstar[b]) {
          pred = true;
          key = ((uint64_t)orderf(sc) << 32) | (uint64_t)(uint32_t)(~(uint32_t)n);
          lp = atomicAdd(&lcnt[b], 1u);
        }
      }
    }
    predv[nt] = pred; keyv[nt] = key; lposv[nt] = lp; bv[nt] = b;
  }
  __syncthreads();
  if (threadIdx.x < 8) {
    uint32_t c = lcnt[threadIdx.x];
    lbase[threadIdx.x] = c ? atomicAdd(&cnt[threadIdx.x], c) : 0u;
  }
  __syncthreads();
  for (int k = 0; k < nt; k++) {
    if (predv[k]) {
      uint32_t pos = lbase[bv[k]] + lposv[k];
      if (pos < CAP) cand[(size_t)bv[k] * CAP + pos] = keyv[k];
    }
  }
}

// Partial rank-by-count, comparison range split JSPLIT ways for occupancy.
__global__ void __launch_bounds__(256) k_rank(const uint64_t* __restrict__ cand,
                                              const uint32_t* __restrict__ cnt,
                                              uint32_t* __restrict__ prank) {
  int blk = blockIdx.x;
  int js = blk % JSPLIT;
  int ic = (blk / JSPLIT) % 32;
  int b  = blk / (JSPLIT * 32);
  int t = threadIdx.x;
  int C = (int)min(cnt[b], (uint32_t)CAP);
  if (ic * 256 >= C) return;
  const uint64_t* g = cand + (size_t)b * CAP;
  int i = ic * 256 + t;
  uint64_t ki = (i < C) ? g[i] : 0ull;

  int q = (C + JSPLIT - 1) / JSPLIT;
  int j0 = js * q;
  int j1 = j0 + q < C ? j0 + q : C;
  if (j0 >= j1) return;

  __shared__ uint64_t tile[1024];
  int rank = 0;
  for (int base = j0; base < j1; base += 1024) {
#pragma unroll
    for (int u = 0; u < 4; u++) {
      int j = base + u * 256 + t;
      tile[u * 256 + t] = (j < j1) ? g[j] : 0ull;
    }
    __syncthreads();
    int lim = j1 - base < 1024 ? j1 - base : 1024;
    const ulonglong2* t2 = (const ulonglong2*)tile;
    int pairs = lim >> 1;
    int jj = 0;
    for (; jj + 4 <= pairs; jj += 4) {
      ulonglong2 v0 = t2[jj + 0], v1 = t2[jj + 1];
      ulonglong2 v2 = t2[jj + 2], v3 = t2[jj + 3];
      rank += (v0.x > ki) ? 1 : 0; rank += (v0.y > ki) ? 1 : 0;
      rank += (v1.x > ki) ? 1 : 0; rank += (v1.y > ki) ? 1 : 0;
      rank += (v2.x > ki) ? 1 : 0; rank += (v2.y > ki) ? 1 : 0;
      rank += (v3.x > ki) ? 1 : 0; rank += (v3.y > ki) ? 1 : 0;
    }
    for (; jj < pairs; jj++) {
      ulonglong2 v = t2[jj];
      rank += (v.x > ki) ? 1 : 0; rank += (v.y > ki) ? 1 : 0;
    }
    if (lim & 1) rank += (tile[lim - 1] > ki) ? 1 : 0;
    __syncthreads();
  }
  if (i < C && rank) atomicAdd(&prank[b * CAP + i], (uint32_t)rank);
}

// Fused place + gather.
__global__ void __launch_bounds__(256) k_place_gather(
    const uint64_t* __restrict__ cand, const uint32_t* __restrict__ cnt,
    const uint32_t* __restrict__ prank,
    const float* __restrict__ anchors, const float* __restrict__ deltas,
    const int* __restrict__ isz,
    double* __restrict__ tbox, double* __restrict__ tarea,
    float4* __restrict__ tboxf, float* __restrict__ tareaf,
    int* __restrict__ top_n, int* __restrict__ Cnum, int B) {
  int idx = blockIdx.x * blockDim.x + threadIdx.x;
  if (idx >= B * CAP) return;
  int b = idx / CAP, i = idx % CAP;
  int C = (int)min(cnt[b], (uint32_t)CAP);
  if (i == 0) Cnum[b] = C < PRE_K ? C : PRE_K;
  if (i >= C) return;
  uint32_t rank = prank[idx];
  if (rank >= PRE_K) return;
  int n = (int)(~(uint32_t)(cand[idx] & 0xFFFFFFFFull));
  double x1, y1, x2, y2; bool valid;
  decode_box(anchors, deltas, isz, n, b, x1, y1, x2, y2, valid);
  size_t row = (size_t)b * ROWS + rank;
  tbox[row * 4 + 0] = x1;
  tbox[row * 4 + 1] = y1;
  tbox[row * 4 + 2] = x2;
  tbox[row * 4 + 3] = y2;
  double ar = (x2 - x1) * (y2 - y1);
  tarea[row] = ar;
  tboxf[row] = make_float4((float)x1, (float)y1, (float)x2, (float)y2);
  tareaf[row] = (float)ar;
  top_n[b * PRE_K + rank] = n;
}

// Suppression bit tiles: all diagonals + off-diag rc < RC_CH + BAND (cc-rc<=3,
// rc>=RC_CH) for the super-chunk pick chain. Chunk-major transposed layout:
//   maskT[((b*CH + cc)*ROWS + row)*2 + w].
__global__ void __launch_bounds__(64) k_iou_mat(const float4* __restrict__ tboxf,
                                                const float* __restrict__ tareaf,
                                                const double* __restrict__ tbox,
                                                const double* __restrict__ tarea,
                                                const int* __restrict__ Cnum,
                                                uint32_t* __restrict__ maskT) {
  int blk = blockIdx.x;
  int k  = blk % (RC_CH + 4);
  int cc = (blk / (RC_CH + 4)) % CH;
  int b  = blk / ((RC_CH + 4) * CH);
  int rc;
  if (k < RC_CH) {                    // off-diag, low rows
    rc = k;
    if (cc <= rc) return;
  } else {                            // band: j = cc - rc in [0,3]
    int j = k - RC_CH;
    rc = cc - j;
    if (rc < 0) return;
    if (j > 0 && rc < RC_CH) return;  // already covered by off-diag branch
  }
  int C = Cnum[b];
  if (rc * 64 >= C || cc * 64 >= C) return;
  int lane = threadIdx.x;
  size_t bb = (size_t)b * ROWS;

  float4 cb4 = tboxf[bb + (size_t)cc * 64 + lane];
  float  sca = 0.7f * tareaf[bb + (size_t)cc * 64 + lane];
  __shared__ float4 rbx[64];
  __shared__ float  rsa[64];
  rbx[lane] = tboxf[bb + (size_t)rc * 64 + lane];
  rsa[lane] = 0.7f * tareaf[bb + (size_t)rc * 64 + lane];
  __syncthreads();

  bool isdiag = (rc == cc);
  uint32_t res0 = 0u, res1 = 0u;

  for (int i = 0; i < 64; i++) {
    float4 r4 = rbx[i];
    float sra = rsa[i];
    float iw = fminf(r4.z, cb4.z) - fmaxf(r4.x, cb4.x);
    float ih = fminf(r4.w, cb4.w) - fmaxf(r4.y, cb4.y);
    iw = fmaxf(iw, 0.0f); ih = fmaxf(ih, 0.0f);
    float inter = iw * ih;
    float diff = fmaf(1.7f, inter, -(sra + sca));
    bool gt = isdiag ? (lane > i) : true;
    unsigned long long sup   = __ballot(gt && (diff >  IOU_EPS));
    unsigned long long loose = __ballot(gt && (diff > -IOU_EPS));
    unsigned long long border = loose & ~sup;
    if (border) {
      bool mine = (border >> lane) & 1ull;
      bool ex = false;
      if (mine)
        ex = iou_exact(tbox, tarea, bb + (size_t)rc * 64 + i,
                       bb + (size_t)cc * 64 + lane);
      sup |= __ballot(ex);
    }
    if (lane == i) { res0 = (uint32_t)sup; res1 = (uint32_t)(sup >> 32); }
  }
  uint2* seg = (uint2*)(maskT + (((size_t)b * CH + cc) * ROWS + (size_t)rc * 64) * 2);
  seg[lane] = make_uint2(res0, res1);
}

// Greedy resolve over 256-row SUPER-chunks (4 chunks per serial step, 24 steps
// instead of 94). Wave0 holds the 256x256 diagonal band (diag[4]+cross[6]
// uint64/lane, prefetched). Frontier = 8 words; phase A reads precomputed
// mask rows (kept rows < RC_CH*64), phase B computes on the fly with
// wave <-> column-block mapping.
__global__ void __launch_bounds__(256) k_nms_reduce(const uint32_t* __restrict__ maskT,
                                                    const float4* __restrict__ tboxf,
                                                    const float* __restrict__ tareaf,
                                                    const double* __restrict__ tbox,
                                                    const double* __restrict__ tarea,
                                                    const int* __restrict__ Cnum,
                                                    int* __restrict__ keep,
                                                    int* __restrict__ kept_count) {
  int b = blockIdx.x, t = threadIdx.x;
  int wave = t >> 6, lane = t & 63;
  int C = Cnum[b];
  const uint32_t* M = maskT + (size_t)b * CH * ROWS * 2;
  size_t bb = (size_t)b * ROWS;

  __shared__ uint32_t s_f[2][8];
  __shared__ uint32_t kept_lo[POST_K];
  __shared__ uint32_t kept_hi[POST_K];
  __shared__ int s_cnt[3];            // picks this super-chunk: total, lo, hi
  if (t < 16) ((uint32_t*)s_f)[t] = 0u;

  // wave0 band registers for super-chunk 0 (diag q=0..3; cross 01,02,03,12,13,23)
  uint2 dg[4], cx[6];
  if (wave == 0) {
#pragma unroll
    for (int q = 0; q < 4; q++)
      dg[q] = *(const uint2*)(M + (((size_t)q) * ROWS + (size_t)q * 64 + lane) * 2);
    int e = 0;
#pragma unroll
    for (int q = 0; q < 3; q++)
#pragma unroll
      for (int q2 = q + 1; q2 < 4; q2++, e++)
        cx[e] = *(const uint2*)(M + (((size_t)q2) * ROWS + (size_t)q * 64 + lane) * 2);
  }
  __syncthreads();

  int nkept = 0, nlo = 0, nhi = 0;
  for (int s = 0; s < SCH; s++) {
    int c0 = s * 4;
    int base0 = c0 * 64;
    if (base0 >= C) break;
    int cbuf = s & 1;
    if (t < 8) s_f[cbuf ^ 1][t] = 0u;

    // ---- phase A: precomputed mask rows (kept_lo)
    uint32_t f[8] = {0u, 0u, 0u, 0u, 0u, 0u, 0u, 0u};
    for (int k2 = t; k2 < nlo; k2 += 256) {
      uint32_t r = kept_lo[k2];
#pragma unroll
      for (int q = 0; q < 4; q++) {
        if (base0 + q * 64 < C) {
          uint2 v = *(const uint2*)(M + (((size_t)(c0 + q)) * ROWS + r) * 2);
          f[2 * q] |= v.x; f[2 * q + 1] |= v.y;
        }
      }
    }
    // ---- phase B: on-the-fly (kept_hi); wave w <-> col block w
    {
      int baseq = base0 + wave * 64;
      if (nhi > 0 && baseq < C) {
        float4 cb4 = tboxf[bb + baseq + lane];
        float  sca = 0.7f * tareaf[bb + baseq + lane];
        for (int k2 = 0; k2 < nhi; k2++) {
          int r = (int)kept_hi[k2];
          float4 r4 = tboxf[bb + r];
          float sra = 0.7f * tareaf[bb + r];
          float iw = fminf(r4.z, cb4.z) - fmaxf(r4.x, cb4.x);
          float ih = fminf(r4.w, cb4.w) - fmaxf(r4.y, cb4.y);
          iw = fmaxf(iw, 0.0f); ih = fmaxf(ih, 0.0f);
          float inter = iw * ih;
          float diff = fmaf(1.7f, inter, -(sra + sca));
          unsigned long long sup   = __ballot(diff >  IOU_EPS);
          unsigned long long loose = __ballot(diff > -IOU_EPS);
          unsigned long long border = loose & ~sup;
          if (border) {
            bool mine = (border >> lane) & 1ull;
            bool ex = false;
            if (mine) ex = iou_exact(tbox, tarea, bb + r, bb + baseq + lane);
            sup |= __ballot(ex);
          }
          f[2 * wave] |= (uint32_t)sup;
          f[2 * wave + 1] |= (uint32_t)(sup >> 32);
        }
      }
    }
#pragma unroll
    for (int off = 32; off > 0; off >>= 1) {
#pragma unroll
      for (int w = 0; w < 8; w++)
        f[w] |= (uint32_t)__shfl_xor((int)f[w], off, 64);
    }
    if (lane == 0) {
#pragma unroll
      for (int w = 0; w < 8; w++)
        if (f[w]) atomicOr(&s_f[cbuf][w], f[w]);
    }
    __syncthreads();

    if (wave == 0) {
      // assemble suppression + band
      uint64_t sup[4], diag64[4], cross64[6];
#pragma unroll
      for (int q = 0; q < 4; q++) {
        sup[q] = (uint64_t)s_f[cbuf][2 * q] | ((uint64_t)s_f[cbuf][2 * q + 1] << 32);
        int rem = C - (base0 + q * 64);
        if (rem <= 0) sup[q] = ~0ull;
        else if (rem < 64) sup[q] |= ~((1ull << rem) - 1ull);
        diag64[q] = (uint64_t)dg[q].x | ((uint64_t)dg[q].y << 32);
      }
#pragma unroll
      for (int e = 0; e < 6; e++)
        cross64[e] = (uint64_t)cx[e].x | ((uint64_t)cx[e].y << 32);

      // prefetch next super-chunk band (static addresses, clamped)
      int c0n = (s + 1 < SCH) ? (s + 1) * 4 : c0;
      uint2 ndg[4], ncx[6];
#pragma unroll
      for (int q = 0; q < 4; q++) {
        int cc = c0n + q < CH ? c0n + q : CH - 1;
        ndg[q] = *(const uint2*)(M + (((size_t)cc) * ROWS + (size_t)cc * 64 + lane) * 2);
      }
      {
        int e = 0;
#pragma unroll
        for (int q = 0; q < 3; q++)
#pragma unroll
          for (int q2 = q + 1; q2 < 4; q2++, e++) {
            int rc = c0n + q  < CH ? c0n + q  : CH - 1;
            int cc = c0n + q2 < CH ? c0n + q2 : CH - 1;
            ncx[e] = *(const uint2*)(M + (((size_t)cc) * ROWS + (size_t)rc * 64 + lane) * 2);
          }
      }

      // pick chains per 64-block with cross propagation
      uint64_t keptM[4] = {0ull, 0ull, 0ull, 0ull};
      static const int xbase[3] = {0, 3, 5};  // cross64 index base for q=0,1,2
#pragma unroll
      for (int q = 0; q < 4; q++) {
        uint64_t alive = ~sup[q];
        uint64_t m = alive;
        while (m) {
          int i = __builtin_ctzll(m);
          keptM[q] |= 1ull << i;
          sup[q] |= shfl64(diag64[q], i) | (1ull << i);
          if (q < 3) {
            int xb = xbase[q];
            for (int q2 = q + 1; q2 < 4; q2++)
              sup[q2] |= shfl64(cross64[xb + (q2 - q - 1)], i);
          }
          m = alive & ~sup[q];
        }
      }
      // cap at POST_K total picks (trim highest rows)
      int tot = __popcll(keptM[0]) + __popcll(keptM[1]) +
                __popcll(keptM[2]) + __popcll(keptM[3]);
      int allowed = POST_K - nkept;
      if (tot > allowed) {
        for (int q = 3; q >= 0 && tot > allowed; q--) {
          while (tot > allowed && keptM[q]) {
            keptM[q] &= ~(1ull << (63 - __builtin_clzll(keptM[q])));
            tot--;
          }
        }
      }
      // write picks
      int off = 0, lo_add = 0, hi_add = 0;
#pragma unroll
      for (int q = 0; q < 4; q++) {
        uint64_t km = keptM[q];
        int pc = __popcll(km);
        int baseq = base0 + q * 64;
        bool isLo = baseq < RC_CH * 64;
        if ((km >> lane) & 1ull) {
          int pfx = __popcll(km & ((1ull << lane) - 1ull));
          int row = baseq + lane;
          keep[b * POST_K + nkept + off + pfx] = row;
          if (isLo) kept_lo[nlo + lo_add + pfx] = (uint32_t)row;
          else      kept_hi[nhi + hi_add + pfx] = (uint32_t)row;
        }
        off += pc;
        if (isLo) lo_add += pc; else hi_add += pc;
      }
      if (lane == 0) { s_cnt[0] = off; s_cnt[1] = lo_add; s_cnt[2] = hi_add; }
#pragma unroll
      for (int q = 0; q < 4; q++) dg[q] = ndg[q];
#pragma unroll
      for (int e = 0; e < 6; e++) cx[e] = ncx[e];
    }
    __syncthreads();

    nkept += s_cnt[0]; nlo += s_cnt[1]; nhi += s_cnt[2];
    if (nkept >= POST_K) break;
  }
  if (t == 0) kept_count[b] = nkept;
}

__global__ void k_output(const int* __restrict__ keep,
                         const int* __restrict__ kept_count,
                         const int* __restrict__ top_n,
                         const double* __restrict__ tbox,
                         const float* __restrict__ logits,
                         const float* __restrict__ deltas,
                         float* __restrict__ out, int B) {
  int idx = blockIdx.x * blockDim.x + threadIdx.x;
  int M = B * POST_K;
  if (idx >= M) return;
  int b = idx / POST_K, s = idx % POST_K;
  float p0 = 0.f, p1 = 0.f, p2 = 0.f, p3 = 0.f;
  float ob = 0.f, d0 = 0.f, d1 = 0.f, d2 = 0.f, d3 = 0.f;
  float bi = -1.0f, okv = 0.0f;
  if (s < kept_count[b]) {
    int j = keep[b * POST_K + s];
    int n = top_n[b * PRE_K + j];
    const double* p = &tbox[((size_t)b * ROWS + j) * 4];
    p0 = (float)p[0]; p1 = (float)p[1]; p2 = (float)p[2]; p3 = (float)p[3];
    ob = logits[n];
    d0 = deltas[4 * n + 0]; d1 = deltas[4 * n + 1];
    d2 = deltas[4 * n + 2]; d3 = deltas[4 * n + 3];
    bi = (float)b; okv = 1.0f;
  }
  out[idx * 4 + 0] = p0;
  out[idx * 4 + 1] = p1;
  out[idx * 4 + 2] = p2;
  out[idx * 4 + 3] = p3;
  out[4 * M + idx] = bi;
  out[5 * M + idx] = ob;
  out[6 * M + idx * 4 + 0] = d0;
  out[6 * M + idx * 4 + 1] = d1;
  out[6 * M + idx * 4 + 2] = d2;
  out[6 * M + idx * 4 + 3] = d3;
  out[10 * M + idx] = okv;
}

// ---- launch -----------------------------------------------------------------

extern "C" void kernel_launch(void* const* d_in, const int* in_sizes, int n_in,
                              void* d_out, int out_size, void* d_ws, size_t ws_size,
                              hipStream_t stream) {
  const float* anchors = (const float*)d_in[0];
  const int*   bix     = (const int*)d_in[1];
  const int*   isz     = (const int*)d_in[2];
  const float* logits  = (const float*)d_in[3];
  const float* deltas  = (const float*)d_in[4];
  float* out = (float*)d_out;

  int N = in_sizes[1];
  int B = in_sizes[2] / 2;

  uintptr_t p = (uintptr_t)d_ws;
  double*   tbox   = (double*)p;    p += (size_t)B * ROWS * 4 * sizeof(double);
  double*   tarea  = (double*)p;    p += (size_t)B * ROWS * sizeof(double);
  uint64_t* cand   = (uint64_t*)p;  p += (size_t)B * CAP * sizeof(uint64_t);
  float*    scores = (float*)p;     p += (size_t)N * sizeof(float);
  uint32_t* hist   = (uint32_t*)p;  p += (size_t)B * BINS * sizeof(uint32_t);
  uint32_t* prank  = (uint32_t*)p;  p += (size_t)B * CAP * sizeof(uint32_t);
  int*      top_n    = (int*)p;     p += (size_t)B * PRE_K * sizeof(int);
  int*      keep     = (int*)p;     p += (size_t)B * POST_K * sizeof(int);
  uint32_t* cnt      = (uint32_t*)p; p += (size_t)B * sizeof(uint32_t);
  uint32_t* bstar    = (uint32_t*)p; p += (size_t)B * sizeof(uint32_t);
  int*      Cnum     = (int*)p;      p += (size_t)B * sizeof(int);
  int*      kept_cnt = (int*)p;      p += (size_t)B * sizeof(int);
  p = (p + 255) & ~(uintptr_t)255;
  uint32_t* maskT    = (uint32_t*)p; p += (size_t)B * CH * ROWS * 2 * sizeof(uint32_t);
  // f32 box mirror overlays `scores` (dead after k_compact)
  float4*   tboxf  = (float4*)scores;
  float*    tareaf = (float*)(scores + (size_t)B * ROWS * 4);
  (void)ws_size; (void)n_in; (void)out_size;

  int initN = B * CAP;   // covers prank (largest), hist, cnt
  k_init<<<(initN + 255) / 256, 256, 0, stream>>>(hist, cnt, prank, B);
  k_score<<<(N + 4095) / 4096, 256, 0, stream>>>(anchors, bix, isz, logits, deltas,
                                                 scores, hist, N);
  k_scan<<<B, BINS, 0, stream>>>(hist, bstar);
  k_compact<<<(N + 8191) / 8192, 1024, 0, stream>>>(scores, bix, bstar, cnt, cand, N);
  k_rank<<<B * 32 * JSPLIT, 256, 0, stream>>>(cand, cnt, prank);
  k_place_gather<<<(B * CAP + 255) / 256, 256, 0, stream>>>(cand, cnt, prank,
                                                            anchors, deltas, isz,
                                                            tbox, tarea, tboxf,
                                                            tareaf, top_n, Cnum, B);
  k_iou_mat<<<B * CH * (RC_CH + 4), 64, 0, stream>>>(tboxf, tareaf, tbox, tarea,
                                                     Cnum, maskT);
  k_nms_reduce<<<B, 256, 0, stream>>>(maskT, tboxf, tareaf, tbox, tarea, Cnum,
                                      keep, kept_cnt);
  k_output<<<(B * POST_K + 255) / 256, 256, 0, stream>>>(keep, kept_cnt, top_n,
                                                         tbox, logits, deltas,
                                                         out, B);
}

// Round 14
// 362.407 us; speedup vs baseline: 1.1100x; 1.1100x over previous
//
#include <hip/hip_runtime.h>
#include <stdint.h>

#define PRE_K   6000
#define POST_K  1000
#define CAP     8192      // candidate buffer per batch
#define BINS    1024
#define ROWS    6016      // 94*64, padded row count for NMS
#define CH      94        // ROWS/64 chunks
#define SCH2    (CH / 2)  // 128-row steps (47)
#define RC_CH   32        // off-diag mask tiles computed only for rc < RC_CH (+cross band)
#define JSPLIT  4         // k_rank comparison-range split
#define NEGF    -1000000000.0f
#define IOU_EPS 16.0f     // f32 decision margin; f32 abs error bound ~2

// ---- helpers ----------------------------------------------------------------

__device__ __forceinline__ uint32_t orderf(float f) {
  uint32_t u = __float_as_uint(f);
  return (u & 0x80000000u) ? ~u : (u | 0x80000000u);
}

__device__ __forceinline__ int score_bin(float sc) {
  int bin = (int)floorf((sc + 12.0f) * ((float)BINS / 24.0f));
  return bin < 0 ? 0 : (bin > BINS - 1 ? BINS - 1 : bin);
}

__device__ __forceinline__ int bin_slot(int bin) {
  return ((bin & 15) << 6) | (bin >> 4);
}

__device__ __forceinline__ uint64_t shfl64(uint64_t v, int src) {
  return (uint64_t)__shfl((long long)v, src, 64);
}

// full double-precision decode, matching the float64 numpy reference
__device__ __forceinline__ void decode_box(
    const float* __restrict__ anchors, const float* __restrict__ deltas,
    const int* __restrict__ isz, int n, int b,
    double& x1, double& y1, double& x2, double& y2, bool& valid) {
  double ax1 = (double)anchors[4 * n + 0], ay1 = (double)anchors[4 * n + 1];
  double ax2 = (double)anchors[4 * n + 2], ay2 = (double)anchors[4 * n + 3];
  double aw = ax2 - ax1, ah = ay2 - ay1;
  double acx = ax1 + 0.5 * aw, acy = ay1 + 0.5 * ah;
  double tx = (double)deltas[4 * n + 0], ty = (double)deltas[4 * n + 1];
  double tw = (double)deltas[4 * n + 2], th = (double)deltas[4 * n + 3];
  tw = tw < -10.0 ? -10.0 : (tw > 10.0 ? 10.0 : tw);
  th = th < -10.0 ? -10.0 : (th > 10.0 ? 10.0 : th);
  double px = acx + tx * aw, py = acy + ty * ah;
  double pw = aw * exp(tw), ph = ah * exp(th);
  double H = (double)isz[2 * b + 0], W = (double)isz[2 * b + 1];
  double wm = W - 1.0, hm = H - 1.0;
  x1 = px - 0.5 * pw; y1 = py - 0.5 * ph;
  x2 = px + 0.5 * pw; y2 = py + 0.5 * ph;
  x1 = fmin(fmax(x1, 0.0), wm); x2 = fmin(fmax(x2, 0.0), wm);
  y1 = fmin(fmax(y1, 0.0), hm); y2 = fmin(fmax(y2, 0.0), hm);
  valid = (x2 - x1 >= 16.0) && (y2 - y1 >= 16.0);
}

// exact f64 suppression test (bit-identical to the verified R2 path)
__device__ __forceinline__ bool iou_exact(const double* __restrict__ tbox,
                                          const double* __restrict__ tarea,
                                          size_t ri, size_t ci) {
  const double* pr = &tbox[ri * 4];
  const double* pc = &tbox[ci * 4];
  double w = fmin(pr[2], pc[2]) - fmax(pr[0], pc[0]); w = w > 0.0 ? w : 0.0;
  double h = fmin(pr[3], pc[3]) - fmax(pr[1], pc[1]); h = h > 0.0 ? h : 0.0;
  double it = w * h;
  return it > 0.7 * (tarea[ri] + tarea[ci] - it + 1e-9);
}

// ---- kernels ----------------------------------------------------------------

__global__ void k_init(uint32_t* hist, uint32_t* cnt, uint32_t* prank, int B) {
  int i = blockIdx.x * blockDim.x + threadIdx.x;
  if (i < B * BINS) hist[i] = 0u;
  if (i < B) cnt[i] = 0u;
  if (i < B * CAP) prank[i] = 0u;
}

// Decode + validity + LDS-privatized histogram.
__global__ void __launch_bounds__(256) k_score(const float* __restrict__ anchors,
                                               const int* __restrict__ bix,
                                               const int* __restrict__ isz,
                                               const float* __restrict__ logits,
                                               const float* __restrict__ deltas,
                                               float* __restrict__ scores,
                                               uint32_t* __restrict__ hist, int N) {
  const int SPAN = 4096;
  int start = blockIdx.x * SPAN;
  int end = start + SPAN < N ? start + SPAN : N;
  __shared__ uint32_t lh[2][BINS];
  for (int i = threadIdx.x; i < 2 * BINS; i += 256) ((uint32_t*)lh)[i] = 0u;
  __shared__ int s_b0, s_b1;
  if (threadIdx.x == 0) { s_b0 = bix[start]; s_b1 = bix[end - 1]; }
  __syncthreads();
  int b0 = s_b0, b1 = s_b1;

  for (int n = start + (int)threadIdx.x; n < end; n += 256) {
    int b = bix[n];
    double x1, y1, x2, y2; bool valid;
    decode_box(anchors, deltas, isz, n, b, x1, y1, x2, y2, valid);
    float sc = valid ? logits[n] : NEGF;
    scores[n] = sc;
    if (valid) {
      int bin = score_bin(sc);
      if (b == b0)      atomicAdd(&lh[0][bin], 1u);
      else if (b == b1) atomicAdd(&lh[1][bin], 1u);
      else              atomicAdd(&hist[b * BINS + bin_slot(bin)], 1u);
    }
  }
  __syncthreads();
  for (int bin = threadIdx.x; bin < BINS; bin += 256) {
    uint32_t c0 = lh[0][bin];
    if (c0) atomicAdd(&hist[b0 * BINS + bin_slot(bin)], c0);
    if (b1 != b0) {
      uint32_t c1 = lh[1][bin];
      if (c1) atomicAdd(&hist[b1 * BINS + bin_slot(bin)], c1);
    }
  }
}

__global__ void k_scan(const uint32_t* __restrict__ hist, uint32_t* __restrict__ bstar) {
  __shared__ uint32_t s[BINS];
  __shared__ int bs;
  int b = blockIdx.x, t = threadIdx.x;
  s[t] = hist[b * BINS + bin_slot(t)];
  if (t == 0) bs = 0;
  __syncthreads();
  for (int off = 1; off < BINS; off <<= 1) {
    uint32_t v = (t + off < BINS) ? s[t + off] : 0u;
    __syncthreads();
    s[t] += v;
    __syncthreads();
  }
  if (s[t] >= PRE_K) atomicMax(&bs, t);
  __syncthreads();
  if (t == 0) bstar[b] = (uint32_t)bs;
}

// Block-aggregated compaction.
__global__ void __launch_bounds__(1024) k_compact(const float* __restrict__ scores,
                                                  const int* __restrict__ bix,
                                                  const uint32_t* __restrict__ bstar,
                                                  uint32_t* __restrict__ cnt,
                                                  uint64_t* __restrict__ cand, int N) {
  const int SPAN = 8192;
  int start = blockIdx.x * SPAN;
  int end = start + SPAN < N ? start + SPAN : N;
  __shared__ uint32_t lcnt[8], lbase[8];
  if (threadIdx.x < 8) lcnt[threadIdx.x] = 0u;
  __syncthreads();

  bool     predv[8];
  uint64_t keyv[8];
  uint32_t lposv[8];
  int      bv[8];
  int nt = 0;
  for (int base = start; base < end; base += 1024, nt++) {
    int n = base + (int)threadIdx.x;
    bool pred = false; int b = 0; uint64_t key = 0ull; uint32_t lp = 0u;
    if (n < end) {
      float sc = scores[n];
      if (sc > 0.5f * NEGF) {
        b = bix[n];
        if ((uint32_t)score_bin(sc) >= bstar[b]) {
          pred = true;
          key = ((uint64_t)orderf(sc) << 32) | (uint64_t)(uint32_t)(~(uint32_t)n);
          lp = atomicAdd(&lcnt[b], 1u);
        }
      }
    }
    predv[nt] = pred; keyv[nt] = key; lposv[nt] = lp; bv[nt] = b;
  }
  __syncthreads();
  if (threadIdx.x < 8) {
    uint32_t c = lcnt[threadIdx.x];
    lbase[threadIdx.x] = c ? atomicAdd(&cnt[threadIdx.x], c) : 0u;
  }
  __syncthreads();
  for (int k = 0; k < nt; k++) {
    if (predv[k]) {
      uint32_t pos = lbase[bv[k]] + lposv[k];
      if (pos < CAP) cand[(size_t)bv[k] * CAP + pos] = keyv[k];
    }
  }
}

// Partial rank-by-count, comparison range split JSPLIT ways for occupancy.
__global__ void __launch_bounds__(256) k_rank(const uint64_t* __restrict__ cand,
                                              const uint32_t* __restrict__ cnt,
                                              uint32_t* __restrict__ prank) {
  int blk = blockIdx.x;
  int js = blk % JSPLIT;
  int ic = (blk / JSPLIT) % 32;
  int b  = blk / (JSPLIT * 32);
  int t = threadIdx.x;
  int C = (int)min(cnt[b], (uint32_t)CAP);
  if (ic * 256 >= C) return;
  const uint64_t* g = cand + (size_t)b * CAP;
  int i = ic * 256 + t;
  uint64_t ki = (i < C) ? g[i] : 0ull;

  int q = (C + JSPLIT - 1) / JSPLIT;
  int j0 = js * q;
  int j1 = j0 + q < C ? j0 + q : C;
  if (j0 >= j1) return;

  __shared__ uint64_t tile[1024];
  int rank = 0;
  for (int base = j0; base < j1; base += 1024) {
#pragma unroll
    for (int u = 0; u < 4; u++) {
      int j = base + u * 256 + t;
      tile[u * 256 + t] = (j < j1) ? g[j] : 0ull;
    }
    __syncthreads();
    int lim = j1 - base < 1024 ? j1 - base : 1024;
    const ulonglong2* t2 = (const ulonglong2*)tile;
    int pairs = lim >> 1;
    int jj = 0;
    for (; jj + 4 <= pairs; jj += 4) {
      ulonglong2 v0 = t2[jj + 0], v1 = t2[jj + 1];
      ulonglong2 v2 = t2[jj + 2], v3 = t2[jj + 3];
      rank += (v0.x > ki) ? 1 : 0; rank += (v0.y > ki) ? 1 : 0;
      rank += (v1.x > ki) ? 1 : 0; rank += (v1.y > ki) ? 1 : 0;
      rank += (v2.x > ki) ? 1 : 0; rank += (v2.y > ki) ? 1 : 0;
      rank += (v3.x > ki) ? 1 : 0; rank += (v3.y > ki) ? 1 : 0;
    }
    for (; jj < pairs; jj++) {
      ulonglong2 v = t2[jj];
      rank += (v.x > ki) ? 1 : 0; rank += (v.y > ki) ? 1 : 0;
    }
    if (lim & 1) rank += (tile[lim - 1] > ki) ? 1 : 0;
    __syncthreads();
  }
  if (i < C && rank) atomicAdd(&prank[b * CAP + i], (uint32_t)rank);
}

// Fused place + gather.
__global__ void __launch_bounds__(256) k_place_gather(
    const uint64_t* __restrict__ cand, const uint32_t* __restrict__ cnt,
    const uint32_t* __restrict__ prank,
    const float* __restrict__ anchors, const float* __restrict__ deltas,
    const int* __restrict__ isz,
    double* __restrict__ tbox, double* __restrict__ tarea,
    float4* __restrict__ tboxf, float* __restrict__ tareaf,
    int* __restrict__ top_n, int* __restrict__ Cnum, int B) {
  int idx = blockIdx.x * blockDim.x + threadIdx.x;
  if (idx >= B * CAP) return;
  int b = idx / CAP, i = idx % CAP;
  int C = (int)min(cnt[b], (uint32_t)CAP);
  if (i == 0) Cnum[b] = C < PRE_K ? C : PRE_K;
  if (i >= C) return;
  uint32_t rank = prank[idx];
  if (rank >= PRE_K) return;
  int n = (int)(~(uint32_t)(cand[idx] & 0xFFFFFFFFull));
  double x1, y1, x2, y2; bool valid;
  decode_box(anchors, deltas, isz, n, b, x1, y1, x2, y2, valid);
  size_t row = (size_t)b * ROWS + rank;
  tbox[row * 4 + 0] = x1;
  tbox[row * 4 + 1] = y1;
  tbox[row * 4 + 2] = x2;
  tbox[row * 4 + 3] = y2;
  double ar = (x2 - x1) * (y2 - y1);
  tarea[row] = ar;
  tboxf[row] = make_float4((float)x1, (float)y1, (float)x2, (float)y2);
  tareaf[row] = (float)ar;
  top_n[b * PRE_K + rank] = n;
}

// Suppression bit tiles: all diagonals + off-diag rc < RC_CH + cross band
// (cc = rc+1, rc >= RC_CH) for the 128-row step pick chain. Chunk-major
// transposed layout: maskT[((b*CH + cc)*ROWS + row)*2 + w].
__global__ void __launch_bounds__(64) k_iou_mat(const float4* __restrict__ tboxf,
                                                const float* __restrict__ tareaf,
                                                const double* __restrict__ tbox,
                                                const double* __restrict__ tarea,
                                                const int* __restrict__ Cnum,
                                                uint32_t* __restrict__ maskT) {
  int blk = blockIdx.x;
  int k  = blk % (RC_CH + 2);
  int cc = (blk / (RC_CH + 2)) % CH;
  int b  = blk / ((RC_CH + 2) * CH);
  int rc;
  if (k < RC_CH) {                    // off-diag, low rows
    rc = k;
    if (cc <= rc) return;
  } else if (k == RC_CH) {            // diagonal
    rc = cc;
  } else {                            // cross band: rc = cc-1
    rc = cc - 1;
    if (rc < RC_CH) return;           // covered by off-diag branch (or rc<0)
  }
  int C = Cnum[b];
  if (rc * 64 >= C || cc * 64 >= C) return;
  int lane = threadIdx.x;
  size_t bb = (size_t)b * ROWS;

  float4 cb4 = tboxf[bb + (size_t)cc * 64 + lane];
  float  sca = 0.7f * tareaf[bb + (size_t)cc * 64 + lane];
  __shared__ float4 rbx[64];
  __shared__ float  rsa[64];
  rbx[lane] = tboxf[bb + (size_t)rc * 64 + lane];
  rsa[lane] = 0.7f * tareaf[bb + (size_t)rc * 64 + lane];
  __syncthreads();

  bool isdiag = (rc == cc);
  uint32_t res0 = 0u, res1 = 0u;

  for (int i = 0; i < 64; i++) {
    float4 r4 = rbx[i];
    float sra = rsa[i];
    float iw = fminf(r4.z, cb4.z) - fmaxf(r4.x, cb4.x);
    float ih = fminf(r4.w, cb4.w) - fmaxf(r4.y, cb4.y);
    iw = fmaxf(iw, 0.0f); ih = fmaxf(ih, 0.0f);
    float inter = iw * ih;
    float diff = fmaf(1.7f, inter, -(sra + sca));
    bool gt = isdiag ? (lane > i) : true;
    unsigned long long sup   = __ballot(gt && (diff >  IOU_EPS));
    unsigned long long loose = __ballot(gt && (diff > -IOU_EPS));
    unsigned long long border = loose & ~sup;
    if (border) {
      bool mine = (border >> lane) & 1ull;
      bool ex = false;
      if (mine)
        ex = iou_exact(tbox, tarea, bb + (size_t)rc * 64 + i,
                       bb + (size_t)cc * 64 + lane);
      sup |= __ballot(ex);
    }
    if (lane == i) { res0 = (uint32_t)sup; res1 = (uint32_t)(sup >> 32); }
  }
  uint2* seg = (uint2*)(maskT + (((size_t)b * CH + cc) * ROWS + (size_t)rc * 64) * 2);
  seg[lane] = make_uint2(res0, res1);
}

// Greedy resolve over 128-row steps (2 chunks per serial step, 47 steps).
// Per pick: 1 diag shfl64 + (q0 only) 1 cross shfl64. Phase A load volume
// identical to the 94-chunk version, in half as many latency rounds. Kept
// rows < RC_CH*64 read precomputed mask; beyond computed on the fly (waves
// split by column-block x half). Output writing fused at the end (kept list
// lives in LDS, in pick order: kept_lo then kept_hi — boundary step-aligned).
__global__ void __launch_bounds__(256) k_nms_reduce(const uint32_t* __restrict__ maskT,
                                                    const float4* __restrict__ tboxf,
                                                    const float* __restrict__ tareaf,
                                                    const double* __restrict__ tbox,
                                                    const double* __restrict__ tarea,
                                                    const int* __restrict__ Cnum,
                                                    const int* __restrict__ top_n,
                                                    const float* __restrict__ logits,
                                                    const float* __restrict__ deltas,
                                                    float* __restrict__ out, int B) {
  int b = blockIdx.x, t = threadIdx.x;
  int wave = t >> 6, lane = t & 63;
  int C = Cnum[b];
  const uint32_t* M = maskT + (size_t)b * CH * ROWS * 2;
  size_t bb = (size_t)b * ROWS;

  __shared__ uint32_t s_f[2][4];
  __shared__ uint32_t kept_lo[POST_K];
  __shared__ uint32_t kept_hi[POST_K];
  __shared__ int s_cnt[3];            // picks this step: total, lo, hi
  if (t < 8) ((uint32_t*)s_f)[t] = 0u;

  // wave0 band registers for step 0: diag chunks 0,1 + cross tile (0,1)
  uint2 dg0, dg1, cx;
  if (wave == 0) {
    dg0 = *(const uint2*)(M + ((size_t)0 * ROWS + (size_t)0 * 64 + lane) * 2);
    dg1 = *(const uint2*)(M + ((size_t)1 * ROWS + (size_t)1 * 64 + lane) * 2);
    cx  = *(const uint2*)(M + ((size_t)1 * ROWS + (size_t)0 * 64 + lane) * 2);
  }
  __syncthreads();

  int nkept = 0, nlo = 0, nhi = 0;
  for (int s = 0; s < SCH2; s++) {
    int c0 = s * 2;
    int base0 = c0 * 64;
    if (base0 >= C) break;
    bool has2 = (base0 + 64) < C;
    int cbuf = s & 1;
    if (t < 4) s_f[cbuf ^ 1][t] = 0u;

    // phase A: precomputed mask rows (kept_lo), 2 uint2 per kept row
    uint32_t f0 = 0u, f1 = 0u, f2 = 0u, f3 = 0u;
    for (int k2 = t; k2 < nlo; k2 += 256) {
      uint32_t r = kept_lo[k2];
      uint2 v0 = *(const uint2*)(M + (((size_t)c0) * ROWS + r) * 2);
      f0 |= v0.x; f1 |= v0.y;
      if (has2) {
        uint2 v1 = *(const uint2*)(M + (((size_t)(c0 + 1)) * ROWS + r) * 2);
        f2 |= v1.x; f3 |= v1.y;
      }
    }
    // phase B: on-the-fly (kept_hi); wave = (half, q) split
    if (nhi > 0) {
      int q = wave & 1, half = wave >> 1;
      int baseq = base0 + q * 64;
      if (baseq < C) {
        float4 cb4 = tboxf[bb + baseq + lane];
        float  sca = 0.7f * tareaf[bb + baseq + lane];
        for (int k2 = half; k2 < nhi; k2 += 2) {
          int r = (int)kept_hi[k2];
          float4 r4 = tboxf[bb + r];
          float sra = 0.7f * tareaf[bb + r];
          float iw = fminf(r4.z, cb4.z) - fmaxf(r4.x, cb4.x);
          float ih = fminf(r4.w, cb4.w) - fmaxf(r4.y, cb4.y);
          iw = fmaxf(iw, 0.0f); ih = fmaxf(ih, 0.0f);
          float inter = iw * ih;
          float diff = fmaf(1.7f, inter, -(sra + sca));
          unsigned long long sup   = __ballot(diff >  IOU_EPS);
          unsigned long long loose = __ballot(diff > -IOU_EPS);
          unsigned long long border = loose & ~sup;
          if (border) {
            bool mine = (border >> lane) & 1ull;
            bool ex = false;
            if (mine) ex = iou_exact(tbox, tarea, bb + r, bb + baseq + lane);
            sup |= __ballot(ex);
          }
          if (q == 0) { f0 |= (uint32_t)sup; f1 |= (uint32_t)(sup >> 32); }
          else        { f2 |= (uint32_t)sup; f3 |= (uint32_t)(sup >> 32); }
        }
      }
    }
#pragma unroll
    for (int off = 32; off > 0; off >>= 1) {
      f0 |= (uint32_t)__shfl_xor((int)f0, off, 64);
      f1 |= (uint32_t)__shfl_xor((int)f1, off, 64);
      f2 |= (uint32_t)__shfl_xor((int)f2, off, 64);
      f3 |= (uint32_t)__shfl_xor((int)f3, off, 64);
    }
    if (lane == 0) {
      if (f0) atomicOr(&s_f[cbuf][0], f0);
      if (f1) atomicOr(&s_f[cbuf][1], f1);
      if (f2) atomicOr(&s_f[cbuf][2], f2);
      if (f3) atomicOr(&s_f[cbuf][3], f3);
    }
    __syncthreads();

    if (wave == 0) {
      uint64_t sup0 = (uint64_t)s_f[cbuf][0] | ((uint64_t)s_f[cbuf][1] << 32);
      uint64_t sup1 = (uint64_t)s_f[cbuf][2] | ((uint64_t)s_f[cbuf][3] << 32);
      {
        int rem0 = C - base0;
        if (rem0 < 64) sup0 |= ~((1ull << rem0) - 1ull);
        int rem1 = C - (base0 + 64);
        if (rem1 <= 0) sup1 = ~0ull;
        else if (rem1 < 64) sup1 |= ~((1ull << rem1) - 1ull);
      }
      uint64_t diag0 = (uint64_t)dg0.x | ((uint64_t)dg0.y << 32);
      uint64_t diag1 = (uint64_t)dg1.x | ((uint64_t)dg1.y << 32);
      uint64_t cross = (uint64_t)cx.x | ((uint64_t)cx.y << 32);
      // prefetch next step's band (static addresses, clamped)
      int c0n = (s + 1 < SCH2) ? (s + 1) * 2 : c0;
      uint2 ndg0 = *(const uint2*)(M + (((size_t)c0n) * ROWS + (size_t)c0n * 64 + lane) * 2);
      uint2 ndg1 = *(const uint2*)(M + (((size_t)(c0n + 1)) * ROWS + (size_t)(c0n + 1) * 64 + lane) * 2);
      uint2 ncx  = *(const uint2*)(M + (((size_t)(c0n + 1)) * ROWS + (size_t)c0n * 64 + lane) * 2);

      uint64_t kept0 = 0ull, kept1 = 0ull;
      {
        uint64_t alive = ~sup0, m = alive;
        while (m) {
          int i = __builtin_ctzll(m);
          kept0 |= 1ull << i;
          sup0 |= shfl64(diag0, i) | (1ull << i);
          sup1 |= shfl64(cross, i);
          m = alive & ~sup0;
        }
      }
      {
        uint64_t alive = ~sup1, m = alive;
        while (m) {
          int i = __builtin_ctzll(m);
          kept1 |= 1ull << i;
          sup1 |= shfl64(diag1, i) | (1ull << i);
          m = alive & ~sup1;
        }
      }
      // cap at POST_K total picks (trim highest rows)
      int tot = __popcll(kept0) + __popcll(kept1);
      int allowed = POST_K - nkept;
      while (tot > allowed && kept1) {
        kept1 &= ~(1ull << (63 - __builtin_clzll(kept1))); tot--;
      }
      while (tot > allowed && kept0) {
        kept0 &= ~(1ull << (63 - __builtin_clzll(kept0))); tot--;
      }
      // write picks to LDS kept lists (keep-order = ascending rows)
      bool isLo = base0 < RC_CH * 64;    // step-aligned boundary: both chunks same side
      int pc0 = __popcll(kept0);
      if ((kept0 >> lane) & 1ull) {
        int pfx = __popcll(kept0 & ((1ull << lane) - 1ull));
        int row = base0 + lane;
        if (isLo) kept_lo[nlo + pfx] = (uint32_t)row;
        else      kept_hi[nhi + pfx] = (uint32_t)row;
      }
      if ((kept1 >> lane) & 1ull) {
        int pfx = pc0 + __popcll(kept1 & ((1ull << lane) - 1ull));
        int row = base0 + 64 + lane;
        if (isLo) kept_lo[nlo + pfx] = (uint32_t)row;
        else      kept_hi[nhi + pfx] = (uint32_t)row;
      }
      if (lane == 0) {
        int pc = pc0 + __popcll(kept1);
        s_cnt[0] = pc;
        s_cnt[1] = isLo ? pc : 0;
        s_cnt[2] = isLo ? 0 : pc;
      }
      dg0 = ndg0; dg1 = ndg1; cx = ncx;
    }
    __syncthreads();

    nkept += s_cnt[0]; nlo += s_cnt[1]; nhi += s_cnt[2];
    if (nkept >= POST_K) break;
  }

  // ---- fused output: block writes its batch's POST_K rows ----
  __syncthreads();
  int M_out = B * POST_K;
  for (int s2 = t; s2 < POST_K; s2 += 256) {
    float p0 = 0.f, p1 = 0.f, p2 = 0.f, p3 = 0.f;
    float ob = 0.f, d0 = 0.f, d1 = 0.f, d2 = 0.f, d3 = 0.f;
    float bi = -1.0f, okv = 0.0f;
    if (s2 < nkept) {
      int j = (s2 < nlo) ? (int)kept_lo[s2] : (int)kept_hi[s2 - nlo];
      int n = top_n[b * PRE_K + j];
      const double* p = &tbox[(bb + j) * 4];
      p0 = (float)p[0]; p1 = (float)p[1]; p2 = (float)p[2]; p3 = (float)p[3];
      ob = logits[n];
      d0 = deltas[4 * n + 0]; d1 = deltas[4 * n + 1];
      d2 = deltas[4 * n + 2]; d3 = deltas[4 * n + 3];
      bi = (float)b; okv = 1.0f;
    }
    int idx = b * POST_K + s2;
    out[idx * 4 + 0] = p0;
    out[idx * 4 + 1] = p1;
    out[idx * 4 + 2] = p2;
    out[idx * 4 + 3] = p3;
    out[4 * M_out + idx] = bi;
    out[5 * M_out + idx] = ob;
    out[6 * M_out + idx * 4 + 0] = d0;
    out[6 * M_out + idx * 4 + 1] = d1;
    out[6 * M_out + idx * 4 + 2] = d2;
    out[6 * M_out + idx * 4 + 3] = d3;
    out[10 * M_out + idx] = okv;
  }
}

// ---- launch -----------------------------------------------------------------

extern "C" void kernel_launch(void* const* d_in, const int* in_sizes, int n_in,
                              void* d_out, int out_size, void* d_ws, size_t ws_size,
                              hipStream_t stream) {
  const float* anchors = (const float*)d_in[0];
  const int*   bix     = (const int*)d_in[1];
  const int*   isz     = (const int*)d_in[2];
  const float* logits  = (const float*)d_in[3];
  const float* deltas  = (const float*)d_in[4];
  float* out = (float*)d_out;

  int N = in_sizes[1];
  int B = in_sizes[2] / 2;

  uintptr_t p = (uintptr_t)d_ws;
  double*   tbox   = (double*)p;    p += (size_t)B * ROWS * 4 * sizeof(double);
  double*   tarea  = (double*)p;    p += (size_t)B * ROWS * sizeof(double);
  uint64_t* cand   = (uint64_t*)p;  p += (size_t)B * CAP * sizeof(uint64_t);
  float*    scores = (float*)p;     p += (size_t)N * sizeof(float);
  uint32_t* hist   = (uint32_t*)p;  p += (size_t)B * BINS * sizeof(uint32_t);
  uint32_t* prank  = (uint32_t*)p;  p += (size_t)B * CAP * sizeof(uint32_t);
  int*      top_n    = (int*)p;     p += (size_t)B * PRE_K * sizeof(int);
  uint32_t* cnt      = (uint32_t*)p; p += (size_t)B * sizeof(uint32_t);
  uint32_t* bstar    = (uint32_t*)p; p += (size_t)B * sizeof(uint32_t);
  int*      Cnum     = (int*)p;      p += (size_t)B * sizeof(int);
  p = (p + 255) & ~(uintptr_t)255;
  uint32_t* maskT    = (uint32_t*)p; p += (size_t)B * CH * ROWS * 2 * sizeof(uint32_t);
  // f32 box mirror overlays `scores` (dead after k_compact)
  float4*   tboxf  = (float4*)scores;
  float*    tareaf = (float*)(scores + (size_t)B * ROWS * 4);
  (void)ws_size; (void)n_in; (void)out_size;

  int initN = B * CAP;   // covers prank (largest), hist, cnt
  k_init<<<(initN + 255) / 256, 256, 0, stream>>>(hist, cnt, prank, B);
  k_score<<<(N + 4095) / 4096, 256, 0, stream>>>(anchors, bix, isz, logits, deltas,
                                                 scores, hist, N);
  k_scan<<<B, BINS, 0, stream>>>(hist, bstar);
  k_compact<<<(N + 8191) / 8192, 1024, 0, stream>>>(scores, bix, bstar, cnt, cand, N);
  k_rank<<<B * 32 * JSPLIT, 256, 0, stream>>>(cand, cnt, prank);
  k_place_gather<<<(B * CAP + 255) / 256, 256, 0, stream>>>(cand, cnt, prank,
                                                            anchors, deltas, isz,
                                                            tbox, tarea, tboxf,
                                                            tareaf, top_n, Cnum, B);
  k_iou_mat<<<B * CH * (RC_CH + 2), 64, 0, stream>>>(tboxf, tareaf, tbox, tarea,
                                                     Cnum, maskT);
  k_nms_reduce<<<B, 256, 0, stream>>>(maskT, tboxf, tareaf, tbox, tarea, Cnum,
                                      top_n, logits, deltas, out, B);
}

// Round 15
// 353.405 us; speedup vs baseline: 1.1382x; 1.0255x over previous
//
#include <hip/hip_runtime.h>
#include <stdint.h>

#define PRE_K   6000
#define POST_K  1000
#define CAP     8192      // candidate buffer per batch
#define BINS    1024
#define ROWS    6016      // 94*64, padded row count for NMS
#define CH      94        // ROWS/64 chunks
#define RC_CH   32        // off-diag mask tiles computed only for rc < RC_CH
#define JSPLIT  8         // k_rank comparison-range split
#define NEGF    -1000000000.0f
#define IOU_EPS 16.0f     // f32 decision margin; f32 abs error bound ~2

// ---- helpers ----------------------------------------------------------------

__device__ __forceinline__ uint32_t orderf(float f) {
  uint32_t u = __float_as_uint(f);
  return (u & 0x80000000u) ? ~u : (u | 0x80000000u);
}

__device__ __forceinline__ int score_bin(float sc) {
  int bin = (int)floorf((sc + 12.0f) * ((float)BINS / 24.0f));
  return bin < 0 ? 0 : (bin > BINS - 1 ? BINS - 1 : bin);
}

__device__ __forceinline__ int bin_slot(int bin) {
  return ((bin & 15) << 6) | (bin >> 4);
}

// full double-precision decode, matching the float64 numpy reference
__device__ __forceinline__ void decode_box(
    const float* __restrict__ anchors, const float* __restrict__ deltas,
    const int* __restrict__ isz, int n, int b,
    double& x1, double& y1, double& x2, double& y2, bool& valid) {
  double ax1 = (double)anchors[4 * n + 0], ay1 = (double)anchors[4 * n + 1];
  double ax2 = (double)anchors[4 * n + 2], ay2 = (double)anchors[4 * n + 3];
  double aw = ax2 - ax1, ah = ay2 - ay1;
  double acx = ax1 + 0.5 * aw, acy = ay1 + 0.5 * ah;
  double tx = (double)deltas[4 * n + 0], ty = (double)deltas[4 * n + 1];
  double tw = (double)deltas[4 * n + 2], th = (double)deltas[4 * n + 3];
  tw = tw < -10.0 ? -10.0 : (tw > 10.0 ? 10.0 : tw);
  th = th < -10.0 ? -10.0 : (th > 10.0 ? 10.0 : th);
  double px = acx + tx * aw, py = acy + ty * ah;
  double pw = aw * exp(tw), ph = ah * exp(th);
  double H = (double)isz[2 * b + 0], W = (double)isz[2 * b + 1];
  double wm = W - 1.0, hm = H - 1.0;
  x1 = px - 0.5 * pw; y1 = py - 0.5 * ph;
  x2 = px + 0.5 * pw; y2 = py + 0.5 * ph;
  x1 = fmin(fmax(x1, 0.0), wm); x2 = fmin(fmax(x2, 0.0), wm);
  y1 = fmin(fmax(y1, 0.0), hm); y2 = fmin(fmax(y2, 0.0), hm);
  valid = (x2 - x1 >= 16.0) && (y2 - y1 >= 16.0);
}

// exact f64 suppression test (bit-identical to the verified R2 path)
__device__ __forceinline__ bool iou_exact(const double* __restrict__ tbox,
                                          const double* __restrict__ tarea,
                                          size_t ri, size_t ci) {
  const double* pr = &tbox[ri * 4];
  const double* pc = &tbox[ci * 4];
  double w = fmin(pr[2], pc[2]) - fmax(pr[0], pc[0]); w = w > 0.0 ? w : 0.0;
  double h = fmin(pr[3], pc[3]) - fmax(pr[1], pc[1]); h = h > 0.0 ? h : 0.0;
  double it = w * h;
  return it > 0.7 * (tarea[ri] + tarea[ci] - it + 1e-9);
}

// ---- kernels ----------------------------------------------------------------

// Decode + validity + LDS-privatized histogram.
__global__ void __launch_bounds__(256) k_score(const float* __restrict__ anchors,
                                               const int* __restrict__ bix,
                                               const int* __restrict__ isz,
                                               const float* __restrict__ logits,
                                               const float* __restrict__ deltas,
                                               float* __restrict__ scores,
                                               uint32_t* __restrict__ hist, int N) {
  const int SPAN = 4096;
  int start = blockIdx.x * SPAN;
  int end = start + SPAN < N ? start + SPAN : N;
  __shared__ uint32_t lh[2][BINS];
  for (int i = threadIdx.x; i < 2 * BINS; i += 256) ((uint32_t*)lh)[i] = 0u;
  __shared__ int s_b0, s_b1;
  if (threadIdx.x == 0) { s_b0 = bix[start]; s_b1 = bix[end - 1]; }
  __syncthreads();
  int b0 = s_b0, b1 = s_b1;

  for (int n = start + (int)threadIdx.x; n < end; n += 256) {
    int b = bix[n];
    double x1, y1, x2, y2; bool valid;
    decode_box(anchors, deltas, isz, n, b, x1, y1, x2, y2, valid);
    float sc = valid ? logits[n] : NEGF;
    scores[n] = sc;
    if (valid) {
      int bin = score_bin(sc);
      if (b == b0)      atomicAdd(&lh[0][bin], 1u);
      else if (b == b1) atomicAdd(&lh[1][bin], 1u);
      else              atomicAdd(&hist[b * BINS + bin_slot(bin)], 1u);
    }
  }
  __syncthreads();
  for (int bin = threadIdx.x; bin < BINS; bin += 256) {
    uint32_t c0 = lh[0][bin];
    if (c0) atomicAdd(&hist[b0 * BINS + bin_slot(bin)], c0);
    if (b1 != b0) {
      uint32_t c1 = lh[1][bin];
      if (c1) atomicAdd(&hist[b1 * BINS + bin_slot(bin)], c1);
    }
  }
}

// Block-aggregated compaction with fused threshold scan (was k_scan): each
// block re-derives bstar for its <=2 batches from hist via LDS suffix-scan.
__global__ void __launch_bounds__(1024) k_compact(const float* __restrict__ scores,
                                                  const int* __restrict__ bix,
                                                  const uint32_t* __restrict__ hist,
                                                  uint32_t* __restrict__ cnt,
                                                  uint64_t* __restrict__ cand, int N) {
  const int SPAN = 8192;
  int start = blockIdx.x * SPAN;
  int end = start + SPAN < N ? start + SPAN : N;
  int t = threadIdx.x;
  __shared__ int s_b0, s_b1;
  __shared__ uint32_t sh[BINS];
  __shared__ int s_bs;
  __shared__ uint32_t lcnt[8], lbase[8];
  if (t == 0) { s_b0 = bix[start]; s_b1 = bix[end - 1]; }
  if (t < 8) lcnt[t] = 0u;
  __syncthreads();
  int b0 = s_b0, b1 = s_b1;

  uint32_t bs0 = 0, bs1 = 0;
  for (int pass = 0; pass < 2; pass++) {
    int b = pass == 0 ? b0 : b1;
    if (pass == 1 && b1 == b0) { bs1 = bs0; break; }
    if (t < BINS) sh[t] = hist[b * BINS + bin_slot(t)];
    if (t == 0) s_bs = 0;
    __syncthreads();
    for (int off = 1; off < BINS; off <<= 1) {
      uint32_t v = (t < BINS && t + off < BINS) ? sh[t + off] : 0u;
      __syncthreads();
      if (t < BINS) sh[t] += v;
      __syncthreads();
    }
    if (t < BINS && sh[t] >= PRE_K) atomicMax(&s_bs, t);
    __syncthreads();
    if (pass == 0) bs0 = (uint32_t)s_bs; else bs1 = (uint32_t)s_bs;
    __syncthreads();
  }

  bool     predv[8];
  uint64_t keyv[8];
  uint32_t lposv[8];
  int      bv[8];
  int nt = 0;
  for (int base = start; base < end; base += 1024, nt++) {
    int n = base + t;
    bool pred = false; int b = 0; uint64_t key = 0ull; uint32_t lp = 0u;
    if (n < end) {
      float sc = scores[n];
      if (sc > 0.5f * NEGF) {
        b = bix[n];
        uint32_t bs = (b == b0) ? bs0 : bs1;
        if ((uint32_t)score_bin(sc) >= bs) {
          pred = true;
          key = ((uint64_t)orderf(sc) << 32) | (uint64_t)(uint32_t)(~(uint32_t)n);
          lp = atomicAdd(&lcnt[b], 1u);
        }
      }
    }
    predv[nt] = pred; keyv[nt] = key; lposv[nt] = lp; bv[nt] = b;
  }
  __syncthreads();
  if (t < 8) {
    uint32_t c = lcnt[t];
    lbase[t] = c ? atomicAdd(&cnt[t], c) : 0u;
  }
  __syncthreads();
  for (int k = 0; k < nt; k++) {
    if (predv[k]) {
      uint32_t pos = lbase[bv[k]] + lposv[k];
      if (pos < CAP) cand[(size_t)bv[k] * CAP + pos] = keyv[k];
    }
  }
}

// Partial rank-by-count; each (b,ic,js) block writes its partial rank slice
// unconditionally (no zero-init needed). grid = B*32*JSPLIT x 256.
__global__ void __launch_bounds__(256) k_rank(const uint64_t* __restrict__ cand,
                                              const uint32_t* __restrict__ cnt,
                                              uint32_t* __restrict__ prank) {
  int blk = blockIdx.x;
  int js = blk % JSPLIT;
  int ic = (blk / JSPLIT) % 32;
  int b  = blk / (JSPLIT * 32);
  int t = threadIdx.x;
  int C = (int)min(cnt[b], (uint32_t)CAP);
  if (ic * 256 >= C) return;
  const uint64_t* g = cand + (size_t)b * CAP;
  int i = ic * 256 + t;
  uint64_t ki = (i < C) ? g[i] : 0ull;

  int q = (C + JSPLIT - 1) / JSPLIT;
  int j0 = js * q;
  int j1 = j0 + q < C ? j0 + q : C;

  __shared__ uint64_t tile[1024];
  int rank = 0;
  for (int base = j0; base < j1; base += 1024) {
#pragma unroll
    for (int u = 0; u < 4; u++) {
      int j = base + u * 256 + t;
      tile[u * 256 + t] = (j < j1) ? g[j] : 0ull;
    }
    __syncthreads();
    int lim = j1 - base < 1024 ? j1 - base : 1024;
    const ulonglong2* t2 = (const ulonglong2*)tile;
    int pairs = lim >> 1;
    int jj = 0;
    for (; jj + 4 <= pairs; jj += 4) {
      ulonglong2 v0 = t2[jj + 0], v1 = t2[jj + 1];
      ulonglong2 v2 = t2[jj + 2], v3 = t2[jj + 3];
      rank += (v0.x > ki) ? 1 : 0; rank += (v0.y > ki) ? 1 : 0;
      rank += (v1.x > ki) ? 1 : 0; rank += (v1.y > ki) ? 1 : 0;
      rank += (v2.x > ki) ? 1 : 0; rank += (v2.y > ki) ? 1 : 0;
      rank += (v3.x > ki) ? 1 : 0; rank += (v3.y > ki) ? 1 : 0;
    }
    for (; jj < pairs; jj++) {
      ulonglong2 v = t2[jj];
      rank += (v.x > ki) ? 1 : 0; rank += (v.y > ki) ? 1 : 0;
    }
    if (lim & 1) rank += (tile[lim - 1] > ki) ? 1 : 0;
    __syncthreads();
  }
  if (i < C) prank[((size_t)b * JSPLIT + js) * CAP + i] = (uint32_t)rank;
}

// Fused place + gather: sums the JSPLIT partial ranks, then decodes the box
// directly into row=rank (f64 + f32 mirrors).
__global__ void __launch_bounds__(256) k_place_gather(
    const uint64_t* __restrict__ cand, const uint32_t* __restrict__ cnt,
    const uint32_t* __restrict__ prank,
    const float* __restrict__ anchors, const float* __restrict__ deltas,
    const int* __restrict__ isz,
    double* __restrict__ tbox, double* __restrict__ tarea,
    float4* __restrict__ tboxf, float* __restrict__ tareaf,
    int* __restrict__ top_n, int* __restrict__ Cnum, int B) {
  int idx = blockIdx.x * blockDim.x + threadIdx.x;
  if (idx >= B * CAP) return;
  int b = idx / CAP, i = idx % CAP;
  int C = (int)min(cnt[b], (uint32_t)CAP);
  if (i == 0) Cnum[b] = C < PRE_K ? C : PRE_K;
  if (i >= C) return;
  uint32_t rank = 0;
#pragma unroll
  for (int js = 0; js < JSPLIT; js++)
    rank += prank[((size_t)b * JSPLIT + js) * CAP + i];
  if (rank >= PRE_K) return;
  int n = (int)(~(uint32_t)(cand[idx] & 0xFFFFFFFFull));
  double x1, y1, x2, y2; bool valid;
  decode_box(anchors, deltas, isz, n, b, x1, y1, x2, y2, valid);
  size_t row = (size_t)b * ROWS + rank;
  tbox[row * 4 + 0] = x1;
  tbox[row * 4 + 1] = y1;
  tbox[row * 4 + 2] = x2;
  tbox[row * 4 + 3] = y2;
  double ar = (x2 - x1) * (y2 - y1);
  tarea[row] = ar;
  tboxf[row] = make_float4((float)x1, (float)y1, (float)x2, (float)y2);
  tareaf[row] = (float)ar;
  top_n[b * PRE_K + rank] = n;
}

// Suppression bit tiles, capped: all diagonals + off-diag rc < RC_CH.
// Chunk-major transposed layout: maskT[((b*CH + cc)*ROWS + row)*2 + w].
__global__ void __launch_bounds__(64) k_iou_mat(const float4* __restrict__ tboxf,
                                                const float* __restrict__ tareaf,
                                                const double* __restrict__ tbox,
                                                const double* __restrict__ tarea,
                                                const int* __restrict__ Cnum,
                                                uint32_t* __restrict__ maskT) {
  int blk = blockIdx.x;
  int k  = blk % (RC_CH + 1);
  int cc = (blk / (RC_CH + 1)) % CH;
  int b  = blk / ((RC_CH + 1) * CH);
  int rc = (k == RC_CH) ? cc : k;
  if (k < RC_CH && cc <= rc) return;
  int C = Cnum[b];
  if (rc * 64 >= C || cc * 64 >= C) return;
  int lane = threadIdx.x;
  size_t bb = (size_t)b * ROWS;

  float4 cb4 = tboxf[bb + (size_t)cc * 64 + lane];
  float  sca = 0.7f * tareaf[bb + (size_t)cc * 64 + lane];
  __shared__ float4 rbx[64];
  __shared__ float  rsa[64];
  rbx[lane] = tboxf[bb + (size_t)rc * 64 + lane];
  rsa[lane] = 0.7f * tareaf[bb + (size_t)rc * 64 + lane];
  __syncthreads();

  bool isdiag = (rc == cc);
  uint32_t res0 = 0u, res1 = 0u;

  for (int i = 0; i < 64; i++) {
    float4 r4 = rbx[i];
    float sra = rsa[i];
    float iw = fminf(r4.z, cb4.z) - fmaxf(r4.x, cb4.x);
    float ih = fminf(r4.w, cb4.w) - fmaxf(r4.y, cb4.y);
    iw = fmaxf(iw, 0.0f); ih = fmaxf(ih, 0.0f);
    float inter = iw * ih;
    float diff = fmaf(1.7f, inter, -(sra + sca));
    bool gt = isdiag ? (lane > i) : true;
    unsigned long long sup   = __ballot(gt && (diff >  IOU_EPS));
    unsigned long long loose = __ballot(gt && (diff > -IOU_EPS));
    unsigned long long border = loose & ~sup;
    if (border) {
      bool mine = (border >> lane) & 1ull;
      bool ex = false;
      if (mine)
        ex = iou_exact(tbox, tarea, bb + (size_t)rc * 64 + i,
                       bb + (size_t)cc * 64 + lane);
      sup |= __ballot(ex);
    }
    if (lane == i) { res0 = (uint32_t)sup; res1 = (uint32_t)(sup >> 32); }
  }
  uint2* seg = (uint2*)(maskT + (((size_t)b * CH + cc) * ROWS + (size_t)rc * 64) * 2);
  seg[lane] = make_uint2(res0, res1);
}

// R12's known-best greedy resolve (94 chunks) + fused output tail.
__global__ void __launch_bounds__(256) k_nms_reduce(const uint32_t* __restrict__ maskT,
                                                    const float4* __restrict__ tboxf,
                                                    const float* __restrict__ tareaf,
                                                    const double* __restrict__ tbox,
                                                    const double* __restrict__ tarea,
                                                    const int* __restrict__ Cnum,
                                                    const int* __restrict__ top_n,
                                                    const float* __restrict__ logits,
                                                    const float* __restrict__ deltas,
                                                    float* __restrict__ out, int B) {
  int b = blockIdx.x, t = threadIdx.x;
  int wave = t >> 6, lane = t & 63;
  int C = Cnum[b];
  const uint32_t* M = maskT + (size_t)b * CH * ROWS * 2;
  size_t bb = (size_t)b * ROWS;

  __shared__ uint32_t s_f[2][2];
  __shared__ uint32_t kept_lo[POST_K];
  __shared__ uint32_t kept_hi[POST_K];
  __shared__ uint64_t s_kept;
  if (t < 4) ((uint32_t*)s_f)[t] = 0u;

  uint32_t d0 = 0u, d1 = 0u;
  if (wave == 0) {
    const uint32_t* rp = M + (size_t)lane * 2;
    d0 = rp[0]; d1 = rp[1];
  }
  __syncthreads();

  int nkept = 0, nlo = 0, nhi = 0;
  for (int c = 0; c < CH; c++) {
    int base = c * 64;
    if (base >= C) break;
    int cbuf = c & 1;
    if (t == 0) { s_f[cbuf ^ 1][0] = 0u; s_f[cbuf ^ 1][1] = 0u; }

    // phase A: precomputed mask rows (kept_lo)
    uint32_t f0 = 0u, f1 = 0u;
    for (int k2 = t; k2 < nlo; k2 += 256) {
      const uint32_t* rp = M + ((size_t)c * ROWS + kept_lo[k2]) * 2;
      f0 |= rp[0]; f1 |= rp[1];
    }
    // phase B: on-the-fly (kept_hi), split across 4 waves
    if (nhi > 0) {
      float4 cb4 = tboxf[bb + base + lane];
      float  sca = 0.7f * tareaf[bb + base + lane];
      for (int k2 = wave; k2 < nhi; k2 += 4) {
        int r = (int)kept_hi[k2];
        float4 r4 = tboxf[bb + r];
        float sra = 0.7f * tareaf[bb + r];
        float iw = fminf(r4.z, cb4.z) - fmaxf(r4.x, cb4.x);
        float ih = fminf(r4.w, cb4.w) - fmaxf(r4.y, cb4.y);
        iw = fmaxf(iw, 0.0f); ih = fmaxf(ih, 0.0f);
        float inter = iw * ih;
        float diff = fmaf(1.7f, inter, -(sra + sca));
        unsigned long long sup   = __ballot(diff >  IOU_EPS);
        unsigned long long loose = __ballot(diff > -IOU_EPS);
        unsigned long long border = loose & ~sup;
        if (border) {
          bool mine = (border >> lane) & 1ull;
          bool ex = false;
          if (mine) ex = iou_exact(tbox, tarea, bb + r, bb + base + lane);
          sup |= __ballot(ex);
        }
        f0 |= (uint32_t)sup; f1 |= (uint32_t)(sup >> 32);
      }
    }
#pragma unroll
    for (int off = 32; off > 0; off >>= 1) {
      f0 |= (uint32_t)__shfl_xor((int)f0, off, 64);
      f1 |= (uint32_t)__shfl_xor((int)f1, off, 64);
    }
    if (lane == 0 && (f0 | f1)) {
      atomicOr(&s_f[cbuf][0], f0);
      atomicOr(&s_f[cbuf][1], f1);
    }
    __syncthreads();

    if (wave == 0) {
      uint64_t sup = (uint64_t)s_f[cbuf][0] | ((uint64_t)s_f[cbuf][1] << 32);
      int rem = C - base;
      if (rem < 64) sup |= ~((1ull << rem) - 1ull);
      uint64_t diag = (uint64_t)d0 | ((uint64_t)d1 << 32);
      int cn = (c + 1 < CH) ? c + 1 : c;
      const uint32_t* rpn = M + ((size_t)cn * ROWS + (size_t)cn * 64 + lane) * 2;
      uint32_t pn0 = rpn[0], pn1 = rpn[1];

      uint64_t keptMask = 0ull;
      uint64_t alive = ~sup;
      uint64_t m = alive;
      while (m) {
        int i = __builtin_ctzll(m);
        keptMask |= 1ull << i;
        uint64_t d = (uint64_t)__shfl((long long)diag, i, 64);
        sup |= d | (1ull << i);
        m = alive & ~sup;
      }
      int allowed = POST_K - nkept;
      int pc = __popcll(keptMask);
      while (pc > allowed) {
        keptMask &= ~(1ull << (63 - __builtin_clzll(keptMask)));
        pc--;
      }
      if (lane == 0) s_kept = keptMask;
      if ((keptMask >> lane) & 1ull) {
        int pfx = __popcll(keptMask & ((1ull << lane) - 1ull));
        int row = base + lane;
        if (c < RC_CH) kept_lo[nlo + pfx] = (uint32_t)row;
        else           kept_hi[nhi + pfx] = (uint32_t)row;
      }
      d0 = pn0; d1 = pn1;
    }
    __syncthreads();

    int pc = __popcll(s_kept);
    nkept += pc;
    if (c < RC_CH) nlo += pc; else nhi += pc;
    if (nkept >= POST_K) break;
  }

  // ---- fused output: block writes its batch's POST_K rows ----
  __syncthreads();
  int M_out = B * POST_K;
  for (int s2 = t; s2 < POST_K; s2 += 256) {
    float p0 = 0.f, p1 = 0.f, p2 = 0.f, p3 = 0.f;
    float ob = 0.f, d0f = 0.f, d1f = 0.f, d2f = 0.f, d3f = 0.f;
    float bi = -1.0f, okv = 0.0f;
    if (s2 < nkept) {
      int j = (s2 < nlo) ? (int)kept_lo[s2] : (int)kept_hi[s2 - nlo];
      int n = top_n[b * PRE_K + j];
      const double* p = &tbox[(bb + j) * 4];
      p0 = (float)p[0]; p1 = (float)p[1]; p2 = (float)p[2]; p3 = (float)p[3];
      ob = logits[n];
      d0f = deltas[4 * n + 0]; d1f = deltas[4 * n + 1];
      d2f = deltas[4 * n + 2]; d3f = deltas[4 * n + 3];
      bi = (float)b; okv = 1.0f;
    }
    int idx = b * POST_K + s2;
    out[idx * 4 + 0] = p0;
    out[idx * 4 + 1] = p1;
    out[idx * 4 + 2] = p2;
    out[idx * 4 + 3] = p3;
    out[4 * M_out + idx] = bi;
    out[5 * M_out + idx] = ob;
    out[6 * M_out + idx * 4 + 0] = d0f;
    out[6 * M_out + idx * 4 + 1] = d1f;
    out[6 * M_out + idx * 4 + 2] = d2f;
    out[6 * M_out + idx * 4 + 3] = d3f;
    out[10 * M_out + idx] = okv;
  }
}

// ---- launch -----------------------------------------------------------------

extern "C" void kernel_launch(void* const* d_in, const int* in_sizes, int n_in,
                              void* d_out, int out_size, void* d_ws, size_t ws_size,
                              hipStream_t stream) {
  const float* anchors = (const float*)d_in[0];
  const int*   bix     = (const int*)d_in[1];
  const int*   isz     = (const int*)d_in[2];
  const float* logits  = (const float*)d_in[3];
  const float* deltas  = (const float*)d_in[4];
  float* out = (float*)d_out;

  int N = in_sizes[1];
  int B = in_sizes[2] / 2;

  uintptr_t p = (uintptr_t)d_ws;
  double*   tbox   = (double*)p;    p += (size_t)B * ROWS * 4 * sizeof(double);
  double*   tarea  = (double*)p;    p += (size_t)B * ROWS * sizeof(double);
  uint64_t* cand   = (uint64_t*)p;  p += (size_t)B * CAP * sizeof(uint64_t);
  float*    scores = (float*)p;     p += (size_t)N * sizeof(float);
  uint32_t* hist   = (uint32_t*)p;  p += (size_t)B * BINS * sizeof(uint32_t);
  uint32_t* cnt    = (uint32_t*)p;  p += (size_t)B * sizeof(uint32_t);   // adjacent to hist
  uint32_t* prank  = (uint32_t*)p;  p += (size_t)B * JSPLIT * CAP * sizeof(uint32_t);
  int*      top_n    = (int*)p;     p += (size_t)B * PRE_K * sizeof(int);
  int*      Cnum     = (int*)p;      p += (size_t)B * sizeof(int);
  p = (p + 255) & ~(uintptr_t)255;
  uint32_t* maskT    = (uint32_t*)p; p += (size_t)B * CH * ROWS * 2 * sizeof(uint32_t);
  // f32 box mirror overlays `scores` (dead after k_compact)
  float4*   tboxf  = (float4*)scores;
  float*    tareaf = (float*)(scores + (size_t)B * ROWS * 4);
  (void)ws_size; (void)n_in; (void)out_size;

  hipMemsetAsync(hist, 0, (size_t)(B * BINS + B) * sizeof(uint32_t), stream);
  k_score<<<(N + 4095) / 4096, 256, 0, stream>>>(anchors, bix, isz, logits, deltas,
                                                 scores, hist, N);
  k_compact<<<(N + 8191) / 8192, 1024, 0, stream>>>(scores, bix, hist, cnt, cand, N);
  k_rank<<<B * 32 * JSPLIT, 256, 0, stream>>>(cand, cnt, prank);
  k_place_gather<<<(B * CAP + 255) / 256, 256, 0, stream>>>(cand, cnt, prank,
                                                            anchors, deltas, isz,
                                                            tbox, tarea, tboxf,
                                                            tareaf, top_n, Cnum, B);
  k_iou_mat<<<B * CH * (RC_CH + 1), 64, 0, stream>>>(tboxf, tareaf, tbox, tarea,
                                                     Cnum, maskT);
  k_nms_reduce<<<B, 256, 0, stream>>>(maskT, tboxf, tareaf, tbox, tarea, Cnum,
                                      top_n, logits, deltas, out, B);
}